// Round 3
// baseline (921.332 us; speedup 1.0000x reference)
//
#include <hip/hip_runtime.h>
#include <math.h>

#define NNODES 10000
#define BATCH  32
#define DDIM   512
#define KSEL   5000
#define EPSV   1e-8f

#define TPB          512
#define GRID         512
#define SCORE_WAVES  2560          // 320 score blocks * 8 waves
#define J3_LIMIT     2320          // waves that get a 4th node per batch
#define ITEM_ROWS    250
#define IPB          (KSEL / ITEM_ROWS)   // 20 items per batch
#define NITEMS       (BATCH * IPB)        // 640
#define SPIN_CAP     8000000u
#define SM_BYTES     49664

// ---------- helpers ----------
__device__ __forceinline__ unsigned mapf(float f) {
    unsigned u = __float_as_uint(f);
    return (u & 0x80000000u) ? ~u : (u | 0x80000000u);
}
__device__ __forceinline__ float ld_ag_f(const float* p) {
    return __hip_atomic_load(p, __ATOMIC_RELAXED, __HIP_MEMORY_SCOPE_AGENT);
}
__device__ __forceinline__ void st_ag_f(float* p, float v) {
    __hip_atomic_store(p, v, __ATOMIC_RELAXED, __HIP_MEMORY_SCOPE_AGENT);
}
__device__ __forceinline__ int ld_ag_i(const int* p) {
    return __hip_atomic_load(p, __ATOMIC_RELAXED, __HIP_MEMORY_SCOPE_AGENT);
}
__device__ __forceinline__ void st_ag_i(int* p, int v) {
    __hip_atomic_store(p, v, __ATOMIC_RELAXED, __HIP_MEMORY_SCOPE_AGENT);
}
__device__ __forceinline__ void st_rel_u(unsigned* p, unsigned v) {
    __hip_atomic_store(p, v, __ATOMIC_RELEASE, __HIP_MEMORY_SCOPE_AGENT);
}

// ---------- K0: w = v/||v||, zero pooled+loss, zero control words ----------
__global__ __launch_bounds__(512) void prep_kernel(const float* __restrict__ v,
                                                   float* __restrict__ w,
                                                   float* __restrict__ out,
                                                   unsigned* __restrict__ ctrl) {
    __shared__ float red[8];
    __shared__ float nrm;
    int tid = threadIdx.x;
    float val = v[tid];
    float sq = val * val;
    for (int off = 32; off > 0; off >>= 1) sq += __shfl_down(sq, off);
    if ((tid & 63) == 0) red[tid >> 6] = sq;
    __syncthreads();
    if (tid == 0) {
        float s = 0.f;
        for (int i = 0; i < 8; i++) s += red[i];
        nrm = sqrtf(s) + EPSV;
    }
    __syncthreads();
    w[tid] = val / nrm;
    for (int i = tid; i < BATCH * DDIM + 1; i += 512) out[i] = 0.f;  // pooled + loss
    if (tid < 65) ctrl[tid] = 0u;  // cnt[32], flag[32], qnext
}

// ---------- radix level (512 threads): k-th largest bin on bits [shift..) ----------
__device__ void radix_level(const float* __restrict__ s, unsigned* hist, unsigned* segsum,
                            unsigned prefix, int prefshift, int shift, int nbins,
                            unsigned k, unsigned* res, int tid) {
    for (int i = tid; i < nbins; i += TPB) hist[i] = 0;
    __syncthreads();
    for (int i = tid; i < NNODES; i += TPB) {
        unsigned u = mapf(s[i]);
        bool cand = (prefshift >= 32) || ((u >> prefshift) == prefix);
        if (cand) atomicAdd(&hist[(u >> shift) & (unsigned)(nbins - 1)], 1u);
    }
    __syncthreads();
    int nseg = nbins >> 5;
    if (tid < nseg) {
        unsigned ssum = 0;
        for (int j = 0; j < 32; j++) ssum += hist[(tid << 5) + j];
        segsum[tid] = ssum;
    }
    __syncthreads();
    if (tid == 0) {
        unsigned cum = 0;
        int seg = 0;
        for (int i = nseg - 1; i >= 0; i--) {
            if (cum + segsum[i] >= k) { seg = i; break; }
            cum += segsum[i];
        }
        int bin = seg << 5;
        for (int j = 31; j >= 0; j--) {
            unsigned h = hist[(seg << 5) + j];
            if (cum + h >= k) { bin = (seg << 5) + j; break; }
            cum += h;
        }
        res[0] = (unsigned)bin;
        res[1] = cum;
    }
    __syncthreads();
}

// ---------- selector: stats, radix K-th largest, loss, compacted (idx,wt) ----------
__device__ void do_select(int b, const float* __restrict__ raw,
                          int* __restrict__ sel_idx, float* __restrict__ sel_wt,
                          float* __restrict__ loss_out,
                          unsigned* cnt, unsigned* flag, char* SM) {
    float*    s      = (float*)SM;                 // 40000 B
    unsigned* hist   = (unsigned*)(SM + 40000);    // 8192 B
    unsigned* segsum = (unsigned*)(SM + 48192);    // 256 B
    float*    fredA  = (float*)(SM + 48448);
    float*    fredB  = (float*)(SM + 48480);
    unsigned* eq_idx = (unsigned*)(SM + 48512);    // 512 B
    int*      icnt   = (int*)(SM + 49024);         // [0]=eq_cnt [1]=sel_cnt
    float*    fb     = (float*)(SM + 49032);       // mu, inv
    unsigned* res    = (unsigned*)(SM + 49040);

    const int tid = threadIdx.x;
    const int lane = tid & 63, wid = tid >> 6;

    if (tid == 0) {
        unsigned it = 0;
        while (__hip_atomic_load(&cnt[b], __ATOMIC_RELAXED, __HIP_MEMORY_SCOPE_AGENT) < (unsigned)NNODES) {
            __builtin_amdgcn_s_sleep(2);
            if (++it > SPIN_CAP) break;
        }
        (void)__hip_atomic_load(&cnt[b], __ATOMIC_ACQUIRE, __HIP_MEMORY_SCOPE_AGENT);
    }
    __syncthreads();

    const float* rb = raw + (size_t)b * NNODES;
    int* sib = sel_idx + (size_t)b * KSEL;
    float* swb = sel_wt + (size_t)b * KSEL;

    float sum = 0.f, sumsq = 0.f;
    for (int i = tid; i < NNODES; i += TPB) {
        float v = ld_ag_f(&rb[i]);
        s[i] = v;
        sum += v; sumsq += v * v;
    }
    for (int off = 32; off > 0; off >>= 1) {
        sum += __shfl_down(sum, off);
        sumsq += __shfl_down(sumsq, off);
    }
    if (lane == 0) { fredA[wid] = sum; fredB[wid] = sumsq; }
    if (tid == 0) { icnt[0] = 0; icnt[1] = 0; }
    __syncthreads();
    if (tid == 0) {
        float ts = 0.f, tq = 0.f;
        for (int i = 0; i < 8; i++) { ts += fredA[i]; tq += fredB[i]; }
        float mu = ts / (float)NNODES;
        float var = tq / (float)NNODES - mu * mu;
        fb[0] = mu; fb[1] = 1.f / (sqrtf(fmaxf(var, 0.f)) + EPSV);
    }
    __syncthreads();
    const float mu = fb[0], inv = fb[1];

    radix_level(s, hist, segsum, 0u, 32, 21, 2048, (unsigned)KSEL, res, tid);
    unsigned t1 = res[0];
    unsigned cg = res[1];
    unsigned k1 = (unsigned)KSEL - cg;
    radix_level(s, hist, segsum, t1, 21, 10, 2048, k1, res, tid);
    unsigned t2 = res[0];
    cg += res[1];
    unsigned k2 = k1 - res[1];
    unsigned p2 = (t1 << 11) | t2;
    radix_level(s, hist, segsum, p2, 10, 0, 1024, k2, res, tid);
    unsigned t3 = res[0];
    cg += res[1];
    const unsigned tu = (p2 << 10) | t3;
    const unsigned count_gt = cg;

    float l = 0.f;
    for (int i = tid; i < NNODES; i += TPB) {
        float v = s[i];
        unsigned m = mapf(v);
        float z = (v - mu) * inv;
        float sig = 1.f / (1.f + expf(-z));
        if (m > tu) {
            l += logf(sig + EPSV);
            int p = atomicAdd(&icnt[1], 1);
            st_ag_i(&sib[p], i); st_ag_f(&swb[p], sig);
        } else if (m < tu) {
            l += logf(1.f - sig + EPSV);
        } else {
            int p = atomicAdd(&icnt[0], 1);
            if (p < 128) eq_idx[p] = (unsigned)i;
        }
    }
    for (int off = 32; off > 0; off >>= 1) l += __shfl_down(l, off);
    if (lane == 0) fredA[wid] = l;
    __syncthreads();
    if (tid == 0) {
        float tl = 0.f;
        for (int i = 0; i < 8; i++) tl += fredA[i];
        int ce = icnt[0];
        int stored = ce > 128 ? 128 : ce;
        for (int i = 1; i < stored; i++) {  // ties ascending (jax prefers lower idx)
            unsigned key = eq_idx[i]; int j = i - 1;
            while (j >= 0 && eq_idx[j] > key) { eq_idx[j + 1] = eq_idx[j]; j--; }
            eq_idx[j + 1] = key;
        }
        int ne = KSEL - (int)count_gt;
        int sc = icnt[1];
        for (int p = 0; p < stored; p++) {
            unsigned idx = eq_idx[p];
            float v = s[idx];
            float z = (v - mu) * inv;
            float sig = 1.f / (1.f + expf(-z));
            if (p < ne) { tl += logf(sig + EPSV); st_ag_i(&sib[sc], (int)idx); st_ag_f(&swb[sc], sig); sc++; }
            else        { tl += logf(1.f - sig + EPSV); }
        }
        if (ce > stored) {  // pathological mass-tie fallback
            float v = s[eq_idx[0]];
            float z = (v - mu) * inv;
            float sig = 1.f / (1.f + expf(-z));
            int extra_sel = ne - stored; if (extra_sel < 0) extra_sel = 0;
            for (int p = 0; p < extra_sel; p++) { st_ag_i(&sib[sc], (int)eq_idx[0]); st_ag_f(&swb[sc], sig); sc++; }
            tl += (float)((ce - stored) - extra_sel) * logf(1.f - sig + EPSV);
        }
        atomicAdd(loss_out, (-tl / (float)NNODES) / (float)BATCH);
    }
    __syncthreads();               // sel stores drained (vmcnt) before publish
    if (tid == 0) st_rel_u(&flag[b], 1u);
}

// ---------- fused persistent kernel ----------
__global__ __launch_bounds__(TPB, 4) void fused_kernel(
        const float* __restrict__ x, const float* __restrict__ w,
        float* __restrict__ raw, int* __restrict__ sel_idx, float* __restrict__ sel_wt,
        float* __restrict__ out, float* __restrict__ loss_out,
        unsigned* __restrict__ ctrl) {
    __shared__ __align__(16) char SM[SM_BYTES];
    unsigned* cnt   = ctrl;
    unsigned* flag  = ctrl + 32;
    unsigned* qnext = ctrl + 64;
    const int tid = threadIdx.x;
    const int r = blockIdx.x & 15;   // role: 0-9 score, 10-14 pool, 15 selector
    const int g = blockIdx.x >> 4;   // 0..31

    if (r < 10) {
        // -------- score role: sweep batches 0..31 front-to-back --------
        const int sb = g * 10 + r;           // 0..319
        const int wv = tid >> 6, lane = tid & 63;
        const int W = sb * 8 + wv;           // 0..2559
        const float4* wp = (const float4*)w;
        const float4 wA = wp[lane], wB = wp[lane + 64];
        int c = J3_LIMIT - sb * 8;
        unsigned bcnt = 24u + (unsigned)(c < 0 ? 0 : (c > 8 ? 8 : c));
        for (int b = 0; b < BATCH; b++) {
            const float* xb = x + (size_t)b * NNODES * DDIM;
            #pragma unroll
            for (int j = 0; j < 4; j++) {
                int n = W + SCORE_WAVES * j;
                if (n < NNODES) {
                    const float4* xp = (const float4*)(xb + (size_t)n * DDIM);
                    float4 a0 = xp[lane], a1 = xp[lane + 64];
                    float d = a0.x * wA.x + a0.y * wA.y + a0.z * wA.z + a0.w * wA.w
                            + a1.x * wB.x + a1.y * wB.y + a1.z * wB.z + a1.w * wB.w;
                    for (int off = 32; off > 0; off >>= 1) d += __shfl_down(d, off);
                    if (lane == 0) st_ag_f(&raw[(size_t)b * NNODES + n], d);
                }
            }
            __syncthreads();  // all waves' agent stores drained
            if (tid == 0)
                __hip_atomic_fetch_add(&cnt[b], bcnt, __ATOMIC_RELEASE, __HIP_MEMORY_SCOPE_AGENT);
        }
    } else if (r == 15) {
        // -------- selector role: one batch per block --------
        do_select(g, raw, sel_idx, sel_wt, loss_out, cnt, flag, SM);
    }

    // -------- pool role: everyone drains the item queue --------
    {
        int*      pidx  = (int*)SM;              // 1000 B
        float*    pwt   = (float*)(SM + 1024);   // 1000 B
        float4*   red   = (float4*)(SM + 2048);  // 8192 B
        unsigned* bcast = (unsigned*)(SM + 10240);
        const int sub = tid >> 7, l = tid & 127;
        for (;;) {
            __syncthreads();  // protect SM reuse (prev iter / prev role)
            if (tid == 0)
                bcast[0] = __hip_atomic_fetch_add(qnext, 1u, __ATOMIC_RELAXED, __HIP_MEMORY_SCOPE_AGENT);
            __syncthreads();
            unsigned it = bcast[0];
            if (it >= (unsigned)NITEMS) break;
            int b = (int)(it / IPB), sp = (int)(it % IPB);
            if (tid == 0) {
                unsigned k = 0;
                while (__hip_atomic_load(&flag[b], __ATOMIC_RELAXED, __HIP_MEMORY_SCOPE_AGENT) == 0u) {
                    __builtin_amdgcn_s_sleep(2);
                    if (++k > SPIN_CAP) break;
                }
                (void)__hip_atomic_load(&flag[b], __ATOMIC_ACQUIRE, __HIP_MEMORY_SCOPE_AGENT);
            }
            __syncthreads();
            int base = b * KSEL + sp * ITEM_ROWS;
            for (int i = tid; i < ITEM_ROWS; i += TPB) {
                pidx[i] = ld_ag_i(&sel_idx[base + i]);
                pwt[i]  = ld_ag_f(&sel_wt[base + i]);
            }
            __syncthreads();
            float4 acc = {0.f, 0.f, 0.f, 0.f};
            for (int rr = sub; rr < ITEM_ROWS; rr += 4) {
                int n = pidx[rr];
                float wt = pwt[rr];
                const float4* xp = (const float4*)(x + ((size_t)b * NNODES + n) * DDIM);
                float4 xv = xp[l];
                acc.x += xv.x * wt; acc.y += xv.y * wt;
                acc.z += xv.z * wt; acc.w += xv.w * wt;
            }
            red[sub * 128 + l] = acc;
            __syncthreads();
            if (sub == 0) {
                float4 t = red[l];
                float4 t1 = red[128 + l], t2 = red[256 + l], t3 = red[384 + l];
                t.x += t1.x + t2.x + t3.x; t.y += t1.y + t2.y + t3.y;
                t.z += t1.z + t2.z + t3.z; t.w += t1.w + t2.w + t3.w;
                const float sc = 1.f / (float)KSEL;
                float* o = out + b * DDIM + l * 4;
                atomicAdd(o + 0, t.x * sc); atomicAdd(o + 1, t.y * sc);
                atomicAdd(o + 2, t.z * sc); atomicAdd(o + 3, t.w * sc);
            }
        }
    }
}

extern "C" void kernel_launch(void* const* d_in, const int* in_sizes, int n_in,
                              void* d_out, int out_size, void* d_ws, size_t ws_size,
                              hipStream_t stream) {
    const float* x = (const float*)d_in[0];   // (B*N, D) fp32
    const float* v = (const float*)d_in[1];   // (D, 1) fp32
    float* out = (float*)d_out;               // pooled (B*D) then loss (1)

    float*    w       = (float*)d_ws;                      // 512
    float*    raw     = w + DDIM;                          // B*N
    int*      sel_idx = (int*)(raw + BATCH * NNODES);      // B*K
    float*    sel_wt  = (float*)(sel_idx + BATCH * KSEL);  // B*K
    unsigned* ctrl    = (unsigned*)(sel_wt + BATCH * KSEL);// cnt[32] flag[32] qnext[1]

    prep_kernel<<<1, DDIM, 0, stream>>>(v, w, out, ctrl);
    fused_kernel<<<GRID, TPB, 0, stream>>>(x, w, raw, sel_idx, sel_wt,
                                           out, out + BATCH * DDIM, ctrl);
}

// Round 4
// 188.082 us; speedup vs baseline: 4.8986x; 4.8986x over previous
//
#include <hip/hip_runtime.h>
#include <math.h>

#define NNODES 10000
#define BATCH  32
#define DDIM   512
#define KSEL   5000
#define EPSV   1e-8f
#define SPAN   125

typedef float f4v __attribute__((ext_vector_type(4)));

// Monotone map: float ordering -> unsigned ordering
__device__ __forceinline__ unsigned mapf(float f) {
    unsigned u = __float_as_uint(f);
    return (u & 0x80000000u) ? ~u : (u | 0x80000000u);
}

// K1: score. 256 thr = 4 waves/block. Each block computes w = v/||v|| locally
// (identical order in every block -> bit-identical), then each wave scores 4
// consecutive nodes with w held in registers.
__global__ __launch_bounds__(256) void score_kernel(const float* __restrict__ x,
                                                    const float* __restrict__ v,
                                                    float* __restrict__ raw,
                                                    float* __restrict__ loss_out) {
    __shared__ float wsh[DDIM];
    __shared__ float red[4];
    const int tid = threadIdx.x;
    const int lane = tid & 63, wv = tid >> 6;

    float v1 = v[tid], v2 = v[tid + 256];
    float sq = v1 * v1 + v2 * v2;
    for (int off = 32; off > 0; off >>= 1) sq += __shfl_down(sq, off);
    if (lane == 0) red[wv] = sq;
    __syncthreads();
    float nrm = sqrtf(red[0] + red[1] + red[2] + red[3]) + EPSV;
    wsh[tid] = v1 / nrm;
    wsh[tid + 256] = v2 / nrm;
    __syncthreads();
    if (blockIdx.x == 0 && tid == 0) loss_out[0] = 0.f;  // ready before select kernel

    const float4* wp = (const float4*)wsh;
    const float4 wA = wp[lane], wB = wp[lane + 64];

    const int base = blockIdx.x * 16 + wv * 4;  // first of this wave's 4 nodes
    const float4* xp = (const float4*)(x + (size_t)base * DDIM);

    float4 a0 = xp[0 * 128 + lane], a1 = xp[0 * 128 + lane + 64];
    float4 b0 = xp[1 * 128 + lane], b1 = xp[1 * 128 + lane + 64];
    float4 c0 = xp[2 * 128 + lane], c1 = xp[2 * 128 + lane + 64];
    float4 e0 = xp[3 * 128 + lane], e1 = xp[3 * 128 + lane + 64];

    float d0 = a0.x * wA.x + a0.y * wA.y + a0.z * wA.z + a0.w * wA.w
             + a1.x * wB.x + a1.y * wB.y + a1.z * wB.z + a1.w * wB.w;
    float d1 = b0.x * wA.x + b0.y * wA.y + b0.z * wA.z + b0.w * wA.w
             + b1.x * wB.x + b1.y * wB.y + b1.z * wB.z + b1.w * wB.w;
    float d2 = c0.x * wA.x + c0.y * wA.y + c0.z * wA.z + c0.w * wA.w
             + c1.x * wB.x + c1.y * wB.y + c1.z * wB.z + c1.w * wB.w;
    float d3 = e0.x * wA.x + e0.y * wA.y + e0.z * wA.z + e0.w * wA.w
             + e1.x * wB.x + e1.y * wB.y + e1.z * wB.z + e1.w * wB.w;

    for (int off = 32; off > 0; off >>= 1) {
        d0 += __shfl_down(d0, off);
        d1 += __shfl_down(d1, off);
        d2 += __shfl_down(d2, off);
        d3 += __shfl_down(d3, off);
    }
    if (lane == 0) {
        float4 r; r.x = d0; r.y = d1; r.z = d2; r.w = d3;
        *(float4*)(raw + base) = r;
    }
}

// One radix level: histogram candidates (prefix-matched) into nbins on bits
// [shift .. shift+log2(nbins)), then find bin of the k-th largest.
// res[0] = bin index, res[1] = count strictly above that bin (within candidates).
__device__ void radix_level(const float* __restrict__ s, unsigned* hist, unsigned* segsum,
                            unsigned prefix, int prefshift, int shift, int nbins,
                            unsigned k, unsigned* res, int tid) {
    for (int i = tid; i < nbins; i += 1024) hist[i] = 0;
    __syncthreads();
    for (int i = tid; i < NNODES; i += 1024) {
        unsigned u = mapf(s[i]);
        bool cand = (prefshift >= 32) || ((u >> prefshift) == prefix);
        if (cand) atomicAdd(&hist[(u >> shift) & (unsigned)(nbins - 1)], 1u);
    }
    __syncthreads();
    int nseg = nbins >> 5;
    if (tid < nseg) {
        unsigned ssum = 0;
        for (int j = 0; j < 32; j++) ssum += hist[(tid << 5) + j];
        segsum[tid] = ssum;
    }
    __syncthreads();
    if (tid == 0) {
        unsigned cum = 0;
        int seg = 0;
        for (int i = nseg - 1; i >= 0; i--) {
            if (cum + segsum[i] >= k) { seg = i; break; }
            cum += segsum[i];
        }
        int bin = seg << 5;
        for (int j = 31; j >= 0; j--) {
            unsigned h = hist[(seg << 5) + j];
            if (cum + h >= k) { bin = (seg << 5) + j; break; }
            cum += h;
        }
        res[0] = (unsigned)bin;
        res[1] = cum;
    }
    __syncthreads();
}

// K2: per-batch stats, radix-select K-th largest, loss, compacted (idx, wt) list.
// Also zeroes this batch's pooled output slice.
__global__ __launch_bounds__(1024) void select_kernel(const float* __restrict__ raw,
                                                      int* __restrict__ sel_idx,
                                                      float* __restrict__ sel_wt,
                                                      float* __restrict__ out_pooled,
                                                      float* __restrict__ loss_out) {
    __shared__ float s[NNODES];
    __shared__ unsigned hist[2048];
    __shared__ unsigned segsum[64];
    __shared__ float fredA[16], fredB[16];
    __shared__ unsigned eq_idx[128];
    __shared__ int eq_cnt;
    __shared__ int sel_cnt;
    __shared__ float fb[2];
    __shared__ unsigned res[2];

    const int tid = threadIdx.x;
    const int lane = tid & 63;
    const int wid = tid >> 6;
    const int b = blockIdx.x;
    const float* rb = raw + (size_t)b * NNODES;
    int* sib = sel_idx + (size_t)b * KSEL;
    float* swb = sel_wt + (size_t)b * KSEL;

    for (int i = tid; i < DDIM; i += 1024) out_pooled[(size_t)b * DDIM + i] = 0.f;

    float sum = 0.f, sumsq = 0.f;
    for (int i = tid; i < NNODES; i += 1024) {
        float v = rb[i];
        s[i] = v;
        sum += v; sumsq += v * v;
    }
    for (int off = 32; off > 0; off >>= 1) {
        sum += __shfl_down(sum, off);
        sumsq += __shfl_down(sumsq, off);
    }
    if (lane == 0) { fredA[wid] = sum; fredB[wid] = sumsq; }
    if (tid == 0) { eq_cnt = 0; sel_cnt = 0; }
    __syncthreads();
    if (tid == 0) {
        float ts = 0.f, tq = 0.f;
        for (int i = 0; i < 16; i++) { ts += fredA[i]; tq += fredB[i]; }
        float mu = ts / (float)NNODES;
        float var = tq / (float)NNODES - mu * mu;
        float sd = sqrtf(fmaxf(var, 0.f));
        fb[0] = mu; fb[1] = 1.f / (sd + EPSV);
    }
    __syncthreads();
    const float mu = fb[0], inv = fb[1];

    // 3-level radix select: bits [31:21], [20:10], [9:0]
    radix_level(s, hist, segsum, 0u, 32, 21, 2048, (unsigned)KSEL, res, tid);
    unsigned t1 = res[0];
    unsigned cg = res[1];
    unsigned k1 = (unsigned)KSEL - cg;
    radix_level(s, hist, segsum, t1, 21, 10, 2048, k1, res, tid);
    unsigned t2 = res[0];
    cg += res[1];
    unsigned k2 = k1 - res[1];
    unsigned p2 = (t1 << 11) | t2;
    radix_level(s, hist, segsum, p2, 10, 0, 1024, k2, res, tid);
    unsigned t3 = res[0];
    cg += res[1];
    const unsigned tu = (p2 << 10) | t3;
    const unsigned count_gt = cg;

    // loss + compaction; collect tied-at-threshold indices
    float l = 0.f;
    for (int i = tid; i < NNODES; i += 1024) {
        float v = s[i];
        unsigned m = mapf(v);
        float z = (v - mu) * inv;
        float sig = 1.f / (1.f + expf(-z));
        if (m > tu) {
            l += logf(sig + EPSV);
            int p = atomicAdd(&sel_cnt, 1);
            sib[p] = i; swb[p] = sig;
        } else if (m < tu) {
            l += logf(1.f - sig + EPSV);
        } else {
            int p = atomicAdd(&eq_cnt, 1);
            if (p < 128) eq_idx[p] = (unsigned)i;
        }
    }
    for (int off = 32; off > 0; off >>= 1) l += __shfl_down(l, off);
    if (lane == 0) fredA[wid] = l;
    __syncthreads();
    if (tid == 0) {
        float tl = 0.f;
        for (int i = 0; i < 16; i++) tl += fredA[i];
        int ce = eq_cnt;
        int stored = ce > 128 ? 128 : ce;
        for (int i = 1; i < stored; i++) {  // ties ascending (jax prefers lower idx)
            unsigned key = eq_idx[i]; int j = i - 1;
            while (j >= 0 && eq_idx[j] > key) { eq_idx[j + 1] = eq_idx[j]; j--; }
            eq_idx[j + 1] = key;
        }
        int ne = KSEL - (int)count_gt;
        int sc = sel_cnt;
        for (int p = 0; p < stored; p++) {
            unsigned idx = eq_idx[p];
            float v = s[idx];
            float z = (v - mu) * inv;
            float sig = 1.f / (1.f + expf(-z));
            if (p < ne) { tl += logf(sig + EPSV); sib[sc] = (int)idx; swb[sc] = sig; sc++; }
            else        { tl += logf(1.f - sig + EPSV); }
        }
        if (ce > stored) {  // pathological mass-tie fallback
            float v = s[eq_idx[0]];
            float z = (v - mu) * inv;
            float sig = 1.f / (1.f + expf(-z));
            int extra_sel = ne - stored; if (extra_sel < 0) extra_sel = 0;
            for (int p = 0; p < extra_sel; p++) { sib[sc] = (int)eq_idx[0]; swb[sc] = sig; sc++; }
            tl += (float)((ce - stored) - extra_sel) * logf(1.f - sig + EPSV);
        }
        float loss_b = -tl / (float)NNODES;
        atomicAdd(loss_out, loss_b / (float)BATCH);
    }
}

// K3: pooled[b,:] += (1/K) * sum over a SPAN of the compacted selection list.
// x loads are non-temporal: each selected row is read exactly once, and nt
// misses don't evict score's L3-resident tail (preserves hits for other blocks).
__global__ __launch_bounds__(128) void pool_kernel(const float* __restrict__ x,
                                                   const int* __restrict__ sel_idx,
                                                   const float* __restrict__ sel_wt,
                                                   float* __restrict__ out) {
    __shared__ int sidx[SPAN];
    __shared__ float swt[SPAN];
    const int spans = KSEL / SPAN;  // 40
    const int b = blockIdx.x / spans;
    const int sp = blockIdx.x % spans;
    const int e0 = sp * SPAN;
    const int tid = threadIdx.x;
    const int* ib = sel_idx + (size_t)b * KSEL + e0;
    const float* wp = sel_wt + (size_t)b * KSEL + e0;
    for (int i = tid; i < SPAN; i += 128) { sidx[i] = ib[i]; swt[i] = wp[i]; }
    __syncthreads();
    const f4v* xb = (const f4v*)x + (size_t)b * NNODES * (DDIM / 4);
    float ax = 0.f, ay = 0.f, az = 0.f, aw = 0.f;
    for (int e = 0; e < SPAN; e++) {
        int n = sidx[e];
        float wt = swt[e];
        f4v xv = __builtin_nontemporal_load(&xb[(size_t)n * (DDIM / 4) + tid]);
        ax += xv.x * wt; ay += xv.y * wt;
        az += xv.z * wt; aw += xv.w * wt;
    }
    const float scale = 1.f / (float)KSEL;
    float* o = out + b * DDIM + tid * 4;
    atomicAdd(o + 0, ax * scale);
    atomicAdd(o + 1, ay * scale);
    atomicAdd(o + 2, az * scale);
    atomicAdd(o + 3, aw * scale);
}

extern "C" void kernel_launch(void* const* d_in, const int* in_sizes, int n_in,
                              void* d_out, int out_size, void* d_ws, size_t ws_size,
                              hipStream_t stream) {
    const float* x = (const float*)d_in[0];   // (B*N, D) fp32
    const float* v = (const float*)d_in[1];   // (D, 1) fp32
    float* out = (float*)d_out;               // pooled (B*D) then loss (1)

    float* raw     = (float*)d_ws;                     // B*N
    int*   sel_idx = (int*)(raw + BATCH * NNODES);     // B*K
    float* sel_wt  = (float*)(sel_idx + BATCH * KSEL); // B*K

    int total = BATCH * NNODES;
    score_kernel<<<total / 16, 256, 0, stream>>>(x, v, raw, out + BATCH * DDIM);
    select_kernel<<<BATCH, 1024, 0, stream>>>(raw, sel_idx, sel_wt, out, out + BATCH * DDIM);
    pool_kernel<<<BATCH * (KSEL / SPAN), 128, 0, stream>>>(x, sel_idx, sel_wt, out);
}